// Round 1
// baseline (932.058 us; speedup 1.0000x reference)
//
#include <hip/hip_runtime.h>

#define NN 100000
#define EE 1600000
#define GG 1000
#define PERG 100
#define KK 30
#define HH 64

__global__ __launch_bounds__(1024) void zero_int(int* p, int n) {
  int i = blockIdx.x * 1024 + threadIdx.x;
  if (i < n) p[i] = 0;
}

__global__ __launch_bounds__(256) void count_kernel(const int* __restrict__ dst,
                                                    int* __restrict__ cnt) {
  int stride = gridDim.x * 256;
  for (int e = blockIdx.x * 256 + threadIdx.x; e < EE; e += stride)
    atomicAdd(&cnt[dst[e]], 1);
}

__global__ __launch_bounds__(1024) void scan_kernel(const int* __restrict__ cnt,
                                                    int* __restrict__ row_start,
                                                    int* __restrict__ cursor) {
  __shared__ int sums[1024];
  int t = threadIdx.x;
  const int C = (NN + 1023) / 1024;
  int lo = t * C;
  int hi = min(lo + C, NN);
  int s = 0;
  for (int i = lo; i < hi; ++i) s += cnt[i];
  sums[t] = s;
  __syncthreads();
  for (int off = 1; off < 1024; off <<= 1) {
    int v = (t >= off) ? sums[t - off] : 0;
    __syncthreads();
    sums[t] += v;
    __syncthreads();
  }
  int pre = (t == 0) ? 0 : sums[t - 1];
  for (int i = lo; i < hi; ++i) {
    row_start[i] = pre;
    cursor[i] = pre;
    pre += cnt[i];
  }
}

__global__ __launch_bounds__(256) void fill_kernel(const int* __restrict__ src,
                                                   const int* __restrict__ dst,
                                                   int* __restrict__ cursor,
                                                   int* __restrict__ eidx) {
  int stride = gridDim.x * 256;
  for (int e = blockIdx.x * 256 + threadIdx.x; e < EE; e += stride) {
    int p = atomicAdd(&cursor[dst[e]], 1);
    eidx[p] = src[e];
  }
}

// X [NN,K] @ (WL[K,64] | WR[K,64]) -> P [NN,64], R [NN,64]
template <int K>
__global__ __launch_bounds__(256) void proj_kernel(const float* __restrict__ X,
                                                   const float* __restrict__ WL,
                                                   const float* __restrict__ WR,
                                                   float* __restrict__ P,
                                                   float* __restrict__ R) {
  constexpr int BM = 64, BMP = 68, WSP = 144, BK = 32;
  __shared__ float xs[K * BMP];   // transposed x tile [k][row]
  __shared__ float ws[BK * WSP];  // swizzled W chunk [k][col-group swizzle]
  const int t = threadIdx.x;
  const int row0 = blockIdx.x * BM;
  constexpr int KQ = K / 4;

  // stage X transposed (coalesced float4 global reads)
  for (int idx = t; idx < BM * KQ; idx += 256) {
    int r = idx / KQ, kq = idx % KQ;
    int row = row0 + r;
    float4 v = make_float4(0.f, 0.f, 0.f, 0.f);
    if (row < NN) v = *reinterpret_cast<const float4*>(&X[(size_t)row * K + kq * 4]);
    xs[(kq * 4 + 0) * BMP + r] = v.x;
    xs[(kq * 4 + 1) * BMP + r] = v.y;
    xs[(kq * 4 + 2) * BMP + r] = v.z;
    xs[(kq * 4 + 3) * BMP + r] = v.w;
  }

  const int tc = t & 15, tr = t >> 4;
  const int wcol = tc * 8 + (tc >> 2) * 4;  // swizzled column offset (<=2-way banks)
  float acc[4][8];
#pragma unroll
  for (int i = 0; i < 4; ++i)
#pragma unroll
    for (int j = 0; j < 8; ++j) acc[i][j] = 0.f;

  for (int k0 = 0; k0 < K; k0 += BK) {
    __syncthreads();
    // stage W chunk (both WL and WR) with swizzle
    for (int idx = t; idx < BK * 16; idx += 256) {
      int kr = idx >> 4, c4 = idx & 15;
      int gcl = c4 >> 1;
      int off = gcl * 8 + (gcl >> 2) * 4 + (c4 & 1) * 4;
      *reinterpret_cast<float4*>(&ws[kr * WSP + off]) =
          *reinterpret_cast<const float4*>(&WL[(k0 + kr) * 64 + c4 * 4]);
      int g2 = gcl + 8;
      int off2 = g2 * 8 + (g2 >> 2) * 4 + (c4 & 1) * 4;
      *reinterpret_cast<float4*>(&ws[kr * WSP + off2]) =
          *reinterpret_cast<const float4*>(&WR[(k0 + kr) * 64 + c4 * 4]);
    }
    __syncthreads();
#pragma unroll 4
    for (int kk = 0; kk < BK; ++kk) {
      int k = k0 + kk;
      float4 a4 = *reinterpret_cast<const float4*>(&xs[k * BMP + tr * 4]);
      float4 b04 = *reinterpret_cast<const float4*>(&ws[kk * WSP + wcol]);
      float4 b14 = *reinterpret_cast<const float4*>(&ws[kk * WSP + wcol + 4]);
      float av[4] = {a4.x, a4.y, a4.z, a4.w};
      float bv[8] = {b04.x, b04.y, b04.z, b04.w, b14.x, b14.y, b14.z, b14.w};
#pragma unroll
      for (int i = 0; i < 4; ++i)
#pragma unroll
        for (int j = 0; j < 8; ++j) acc[i][j] = fmaf(av[i], bv[j], acc[i][j]);
    }
  }

  float* OUT = (tc < 8) ? P : R;
  int cb = (tc & 7) * 8;
#pragma unroll
  for (int i = 0; i < 4; ++i) {
    int row = row0 + tr * 4 + i;
    if (row < NN) {
      float4 lo = make_float4(acc[i][0], acc[i][1], acc[i][2], acc[i][3]);
      float4 hi = make_float4(acc[i][4], acc[i][5], acc[i][6], acc[i][7]);
      *reinterpret_cast<float4*>(&OUT[(size_t)row * 64 + cb]) = lo;
      *reinterpret_cast<float4*>(&OUT[(size_t)row * 64 + cb + 4]) = hi;
    }
  }
}

// one wave per node: h[i] = relu(mean_j P[src_j] + b + R[i])
__global__ __launch_bounds__(256) void agg_kernel(const float* __restrict__ P,
                                                  const float* __restrict__ R,
                                                  const float* __restrict__ bias,
                                                  const int* __restrict__ row_start,
                                                  const int* __restrict__ cnt,
                                                  const int* __restrict__ eidx,
                                                  float* __restrict__ h) {
  int wid = (blockIdx.x * 256 + threadIdx.x) >> 6;
  int lane = threadIdx.x & 63;
  if (wid >= NN) return;
  int base = row_start[wid];
  int deg = cnt[wid];
  float acc0 = 0.f, acc1 = 0.f;
  for (int e0 = 0; e0 < deg; e0 += 64) {
    int m = min(64, deg - e0);
    int idx = (lane < m) ? eidx[base + e0 + lane] : 0;
    int j = 0;
    for (; j + 1 < m; j += 2) {
      int s0 = __shfl(idx, j);
      int s1 = __shfl(idx, j + 1);
      acc0 += P[(size_t)s0 * 64 + lane];
      acc1 += P[(size_t)s1 * 64 + lane];
    }
    if (j < m) {
      int s0 = __shfl(idx, j);
      acc0 += P[(size_t)s0 * 64 + lane];
    }
  }
  float mean = (acc0 + acc1) / fmaxf((float)deg, 1.0f);
  h[(size_t)wid * 64 + lane] = fmaxf(mean + bias[lane] + R[(size_t)wid * 64 + lane], 0.0f);
}

// one block per graph: stable top-30 by last channel, conv1d, MLP head
__global__ __launch_bounds__(128) void head_kernel(const float* __restrict__ h,
                                                   const float* __restrict__ cw,
                                                   const float* __restrict__ cb,
                                                   const float* __restrict__ w1,
                                                   const float* __restrict__ bb1,
                                                   const float* __restrict__ w2,
                                                   const float* __restrict__ bb2,
                                                   float* __restrict__ out) {
  __shared__ float key[PERG];
  __shared__ int sel[KK];
  __shared__ float feat[KK][65];
  __shared__ float cws[32 * 192];
  __shared__ float z[896];
  __shared__ float psum[128];
  const int g = blockIdx.x;
  const int t = threadIdx.x;

  for (int idx = t; idx < 32 * 192; idx += 128) cws[idx] = cw[idx];
  if (t < PERG) key[t] = h[(size_t)(g * PERG + t) * HH + (HH - 1)];
  __syncthreads();

  if (t < PERG) {
    float kv = key[t];
    int r = 0;
    for (int m = 0; m < PERG; ++m) {
      float km = key[m];
      r += (int)((km > kv) || (km == kv && m < t));
    }
    if (r < KK) sel[r] = t;
  }
  __syncthreads();

  for (int idx = t; idx < KK * HH; idx += 128) {
    int r = idx >> 6, f = idx & 63;
    feat[r][f] = h[(size_t)(g * PERG + sel[r]) * HH + f];
  }
  __syncthreads();

  for (int idx = t; idx < 32 * 28; idx += 128) {
    int o = idx / 28, p = idx % 28;
    float acc = cb[o];
#pragma unroll
    for (int tt = 0; tt < 3; ++tt)
      for (int i = 0; i < 64; ++i)
        acc = fmaf(feat[p + tt][i], cws[o * 192 + i * 3 + tt], acc);
    z[o * 28 + p] = fmaxf(acc, 0.f);
  }
  __syncthreads();

  {
    int hh = t & 63, half = t >> 6;
    int q0 = half * 448;
    float acc = 0.f;
    for (int q = 0; q < 448; ++q) acc = fmaf(z[q0 + q], w1[(q0 + q) * 64 + hh], acc);
    psum[t] = acc;
  }
  __syncthreads();

  if (t < 64) {
    float o1 = fmaxf(bb1[t] + psum[t] + psum[t + 64], 0.f);
    float v = o1 * w2[t];
#pragma unroll
    for (int off = 32; off > 0; off >>= 1) v += __shfl_down(v, off);
    if (t == 0) out[g] = v + bb2[0];
  }
}

extern "C" void kernel_launch(void* const* d_in, const int* in_sizes, int n_in,
                              void* d_out, int out_size, void* d_ws, size_t ws_size,
                              hipStream_t stream) {
  const float* x = (const float*)d_in[0];
  const int* src = (const int*)d_in[1];
  const int* dst = (const int*)d_in[2];
  const float* wl1 = (const float*)d_in[4];
  const float* wr1 = (const float*)d_in[5];
  const float* b1 = (const float*)d_in[6];
  const float* wl2 = (const float*)d_in[7];
  const float* wr2 = (const float*)d_in[8];
  const float* b2 = (const float*)d_in[9];
  const float* wl3 = (const float*)d_in[10];
  const float* wr3 = (const float*)d_in[11];
  const float* b3 = (const float*)d_in[12];
  const float* cw = (const float*)d_in[13];
  const float* cb = (const float*)d_in[14];
  const float* w1 = (const float*)d_in[15];
  const float* bb1 = (const float*)d_in[16];
  const float* w2 = (const float*)d_in[17];
  const float* bb2 = (const float*)d_in[18];
  float* out = (float*)d_out;

  char* w = (char*)d_ws;
  auto carve = [&](size_t bytes) {
    char* p = w;
    w += (bytes + 255) & ~(size_t)255;
    return p;
  };
  int* cnt = (int*)carve((size_t)NN * 4);
  int* row_start = (int*)carve((size_t)NN * 4);
  int* cursor = (int*)carve((size_t)NN * 4);
  int* eidx = (int*)carve((size_t)EE * 4);
  float* P = (float*)carve((size_t)NN * 64 * 4);
  float* R = (float*)carve((size_t)NN * 64 * 4);
  float* hbuf = (float*)carve((size_t)NN * 64 * 4);

  zero_int<<<(NN + 1023) / 1024, 1024, 0, stream>>>(cnt, NN);
  count_kernel<<<2048, 256, 0, stream>>>(dst, cnt);
  scan_kernel<<<1, 1024, 0, stream>>>(cnt, row_start, cursor);
  fill_kernel<<<2048, 256, 0, stream>>>(src, dst, cursor, eidx);

  const int projGrid = (NN + 63) / 64;
  const int aggGrid = (NN + 3) / 4;
  proj_kernel<128><<<projGrid, 256, 0, stream>>>(x, wl1, wr1, P, R);
  agg_kernel<<<aggGrid, 256, 0, stream>>>(P, R, b1, row_start, cnt, eidx, hbuf);
  proj_kernel<64><<<projGrid, 256, 0, stream>>>(hbuf, wl2, wr2, P, R);
  agg_kernel<<<aggGrid, 256, 0, stream>>>(P, R, b2, row_start, cnt, eidx, hbuf);
  proj_kernel<64><<<projGrid, 256, 0, stream>>>(hbuf, wl3, wr3, P, R);
  agg_kernel<<<aggGrid, 256, 0, stream>>>(P, R, b3, row_start, cnt, eidx, hbuf);
  head_kernel<<<GG, 128, 0, stream>>>(hbuf, cw, cb, w1, bb1, w2, bb2, out);
}

// Round 2
// 719.798 us; speedup vs baseline: 1.2949x; 1.2949x over previous
//
#include <hip/hip_runtime.h>

#define NN 100000
#define EE 1600000
#define GG 1000
#define PERG 100
#define KK 30
#define HH 64

#define SCAN_CHUNK 1024
#define SCAN_BLOCKS ((NN + SCAN_CHUNK - 1) / SCAN_CHUNK)  // 98

__global__ __launch_bounds__(1024) void zero_int(int* p, int n) {
  int i = blockIdx.x * 1024 + threadIdx.x;
  if (i < n) p[i] = 0;
}

__global__ __launch_bounds__(256) void count_kernel(const int* __restrict__ dst,
                                                    int* __restrict__ cnt) {
  int stride = gridDim.x * 256;
  for (int e = blockIdx.x * 256 + threadIdx.x; e < EE; e += stride)
    atomicAdd(&cnt[dst[e]], 1);
}

// ---- parallel 3-pass scan (replaces 231us single-block scan) ----
__global__ __launch_bounds__(256) void scan_pass1(const int* __restrict__ cnt,
                                                  int* __restrict__ blockSum) {
  const int t = threadIdx.x;
  const int base = blockIdx.x * SCAN_CHUNK + t * 4;
  int s = 0;
#pragma unroll
  for (int j = 0; j < 4; ++j) {
    int i = base + j;
    if (i < NN) s += cnt[i];
  }
#pragma unroll
  for (int off = 32; off > 0; off >>= 1) s += __shfl_xor(s, off, 64);
  __shared__ int waveTot[4];
  if ((t & 63) == 0) waveTot[t >> 6] = s;
  __syncthreads();
  if (t == 0) blockSum[blockIdx.x] = waveTot[0] + waveTot[1] + waveTot[2] + waveTot[3];
}

__global__ __launch_bounds__(128) void scan_pass2(int* __restrict__ blockSum) {
  const int t = threadIdx.x;
  int v = (t < SCAN_BLOCKS) ? blockSum[t] : 0;
  int incl = v;
#pragma unroll
  for (int off = 1; off < 64; off <<= 1) {
    int u = __shfl_up(incl, off, 64);
    if ((t & 63) >= off) incl += u;
  }
  __shared__ int waveTot[2];
  if ((t & 63) == 63) waveTot[t >> 6] = incl;
  __syncthreads();
  if (t >= 64) incl += waveTot[0];
  if (t < SCAN_BLOCKS) blockSum[t] = incl - v;  // exclusive block offset
}

__global__ __launch_bounds__(256) void scan_pass3(const int* __restrict__ cnt,
                                                  const int* __restrict__ blockOff,
                                                  int* __restrict__ row_start,
                                                  int* __restrict__ cursor) {
  const int t = threadIdx.x;
  const int base = blockIdx.x * SCAN_CHUNK + t * 4;
  int v[4];
  int ts = 0;
#pragma unroll
  for (int j = 0; j < 4; ++j) {
    int i = base + j;
    v[j] = (i < NN) ? cnt[i] : 0;
    ts += v[j];
  }
  int incl = ts;
#pragma unroll
  for (int off = 1; off < 64; off <<= 1) {
    int u = __shfl_up(incl, off, 64);
    if ((t & 63) >= off) incl += u;
  }
  __shared__ int waveTot[4];
  const int w = t >> 6;
  if ((t & 63) == 63) waveTot[w] = incl;
  __syncthreads();
  int woff = 0;
#pragma unroll
  for (int k = 0; k < 4; ++k)
    if (k < w) woff += waveTot[k];
  int pre = blockOff[blockIdx.x] + woff + (incl - ts);
#pragma unroll
  for (int j = 0; j < 4; ++j) {
    int i = base + j;
    if (i < NN) {
      row_start[i] = pre;
      cursor[i] = pre;
    }
    pre += v[j];
  }
}

__global__ __launch_bounds__(256) void fill_kernel(const int* __restrict__ src,
                                                   const int* __restrict__ dst,
                                                   int* __restrict__ cursor,
                                                   int* __restrict__ eidx) {
  int stride = gridDim.x * 256;
  for (int e = blockIdx.x * 256 + threadIdx.x; e < EE; e += stride) {
    int p = atomicAdd(&cursor[dst[e]], 1);
    eidx[p] = src[e];
  }
}

// X [NN,K] @ (WL[K,64] | WR[K,64]) -> P [NN,64], R [NN,64]
template <int K>
__global__ __launch_bounds__(256) void proj_kernel(const float* __restrict__ X,
                                                   const float* __restrict__ WL,
                                                   const float* __restrict__ WR,
                                                   float* __restrict__ P,
                                                   float* __restrict__ R) {
  constexpr int BM = 64, BMP = 68, WSP = 144, BK = 32;
  __shared__ float xs[K * BMP];   // transposed x tile [k][row]
  __shared__ float ws[BK * WSP];  // swizzled W chunk [k][col-group swizzle]
  const int t = threadIdx.x;
  const int row0 = blockIdx.x * BM;
  constexpr int KQ = K / 4;

  // stage X transposed (coalesced float4 global reads)
  for (int idx = t; idx < BM * KQ; idx += 256) {
    int r = idx / KQ, kq = idx % KQ;
    int row = row0 + r;
    float4 v = make_float4(0.f, 0.f, 0.f, 0.f);
    if (row < NN) v = *reinterpret_cast<const float4*>(&X[(size_t)row * K + kq * 4]);
    xs[(kq * 4 + 0) * BMP + r] = v.x;
    xs[(kq * 4 + 1) * BMP + r] = v.y;
    xs[(kq * 4 + 2) * BMP + r] = v.z;
    xs[(kq * 4 + 3) * BMP + r] = v.w;
  }

  const int tc = t & 15, tr = t >> 4;
  const int wcol = tc * 8 + (tc >> 2) * 4;  // swizzled column offset (<=2-way banks)
  float acc[4][8];
#pragma unroll
  for (int i = 0; i < 4; ++i)
#pragma unroll
    for (int j = 0; j < 8; ++j) acc[i][j] = 0.f;

  for (int k0 = 0; k0 < K; k0 += BK) {
    __syncthreads();
    // stage W chunk (both WL and WR) with swizzle
    for (int idx = t; idx < BK * 16; idx += 256) {
      int kr = idx >> 4, c4 = idx & 15;
      int gcl = c4 >> 1;
      int off = gcl * 8 + (gcl >> 2) * 4 + (c4 & 1) * 4;
      *reinterpret_cast<float4*>(&ws[kr * WSP + off]) =
          *reinterpret_cast<const float4*>(&WL[(k0 + kr) * 64 + c4 * 4]);
      int g2 = gcl + 8;
      int off2 = g2 * 8 + (g2 >> 2) * 4 + (c4 & 1) * 4;
      *reinterpret_cast<float4*>(&ws[kr * WSP + off2]) =
          *reinterpret_cast<const float4*>(&WR[(k0 + kr) * 64 + c4 * 4]);
    }
    __syncthreads();
#pragma unroll 4
    for (int kk = 0; kk < BK; ++kk) {
      int k = k0 + kk;
      float4 a4 = *reinterpret_cast<const float4*>(&xs[k * BMP + tr * 4]);
      float4 b04 = *reinterpret_cast<const float4*>(&ws[kk * WSP + wcol]);
      float4 b14 = *reinterpret_cast<const float4*>(&ws[kk * WSP + wcol + 4]);
      float av[4] = {a4.x, a4.y, a4.z, a4.w};
      float bv[8] = {b04.x, b04.y, b04.z, b04.w, b14.x, b14.y, b14.z, b14.w};
#pragma unroll
      for (int i = 0; i < 4; ++i)
#pragma unroll
        for (int j = 0; j < 8; ++j) acc[i][j] = fmaf(av[i], bv[j], acc[i][j]);
    }
  }

  float* OUT = (tc < 8) ? P : R;
  int cb = (tc & 7) * 8;
#pragma unroll
  for (int i = 0; i < 4; ++i) {
    int row = row0 + tr * 4 + i;
    if (row < NN) {
      float4 lo = make_float4(acc[i][0], acc[i][1], acc[i][2], acc[i][3]);
      float4 hi = make_float4(acc[i][4], acc[i][5], acc[i][6], acc[i][7]);
      *reinterpret_cast<float4*>(&OUT[(size_t)row * 64 + cb]) = lo;
      *reinterpret_cast<float4*>(&OUT[(size_t)row * 64 + cb + 4]) = hi;
    }
  }
}

// one wave per node: h[i] = relu(mean_j P[src_j] + b + R[i])
__global__ __launch_bounds__(256) void agg_kernel(const float* __restrict__ P,
                                                  const float* __restrict__ R,
                                                  const float* __restrict__ bias,
                                                  const int* __restrict__ row_start,
                                                  const int* __restrict__ cnt,
                                                  const int* __restrict__ eidx,
                                                  float* __restrict__ h) {
  int wid = (blockIdx.x * 256 + threadIdx.x) >> 6;
  int lane = threadIdx.x & 63;
  if (wid >= NN) return;
  int base = row_start[wid];
  int deg = cnt[wid];
  float acc0 = 0.f, acc1 = 0.f;
  for (int e0 = 0; e0 < deg; e0 += 64) {
    int m = min(64, deg - e0);
    int idx = (lane < m) ? eidx[base + e0 + lane] : 0;
    int j = 0;
    for (; j + 1 < m; j += 2) {
      int s0 = __shfl(idx, j);
      int s1 = __shfl(idx, j + 1);
      acc0 += P[(size_t)s0 * 64 + lane];
      acc1 += P[(size_t)s1 * 64 + lane];
    }
    if (j < m) {
      int s0 = __shfl(idx, j);
      acc0 += P[(size_t)s0 * 64 + lane];
    }
  }
  float mean = (acc0 + acc1) / fmaxf((float)deg, 1.0f);
  h[(size_t)wid * 64 + lane] = fmaxf(mean + bias[lane] + R[(size_t)wid * 64 + lane], 0.0f);
}

// one block per graph: stable top-30 by last channel, conv1d, MLP head
__global__ __launch_bounds__(128) void head_kernel(const float* __restrict__ h,
                                                   const float* __restrict__ cw,
                                                   const float* __restrict__ cb,
                                                   const float* __restrict__ w1,
                                                   const float* __restrict__ bb1,
                                                   const float* __restrict__ w2,
                                                   const float* __restrict__ bb2,
                                                   float* __restrict__ out) {
  __shared__ float key[PERG];
  __shared__ int sel[KK];
  __shared__ float feat[KK][65];
  __shared__ float cws[32 * 192];
  __shared__ float z[896];
  __shared__ float psum[128];
  const int g = blockIdx.x;
  const int t = threadIdx.x;

  for (int idx = t; idx < 32 * 192; idx += 128) cws[idx] = cw[idx];
  if (t < PERG) key[t] = h[(size_t)(g * PERG + t) * HH + (HH - 1)];
  __syncthreads();

  if (t < PERG) {
    float kv = key[t];
    int r = 0;
    for (int m = 0; m < PERG; ++m) {
      float km = key[m];
      r += (int)((km > kv) || (km == kv && m < t));
    }
    if (r < KK) sel[r] = t;
  }
  __syncthreads();

  for (int idx = t; idx < KK * HH; idx += 128) {
    int r = idx >> 6, f = idx & 63;
    feat[r][f] = h[(size_t)(g * PERG + sel[r]) * HH + f];
  }
  __syncthreads();

  for (int idx = t; idx < 32 * 28; idx += 128) {
    int o = idx / 28, p = idx % 28;
    float acc = cb[o];
#pragma unroll
    for (int tt = 0; tt < 3; ++tt)
      for (int i = 0; i < 64; ++i)
        acc = fmaf(feat[p + tt][i], cws[o * 192 + i * 3 + tt], acc);
    z[o * 28 + p] = fmaxf(acc, 0.f);
  }
  __syncthreads();

  {
    int hh = t & 63, half = t >> 6;
    int q0 = half * 448;
    float acc = 0.f;
    for (int q = 0; q < 448; ++q) acc = fmaf(z[q0 + q], w1[(q0 + q) * 64 + hh], acc);
    psum[t] = acc;
  }
  __syncthreads();

  if (t < 64) {
    float o1 = fmaxf(bb1[t] + psum[t] + psum[t + 64], 0.f);
    float v = o1 * w2[t];
#pragma unroll
    for (int off = 32; off > 0; off >>= 1) v += __shfl_down(v, off);
    if (t == 0) out[g] = v + bb2[0];
  }
}

extern "C" void kernel_launch(void* const* d_in, const int* in_sizes, int n_in,
                              void* d_out, int out_size, void* d_ws, size_t ws_size,
                              hipStream_t stream) {
  const float* x = (const float*)d_in[0];
  const int* src = (const int*)d_in[1];
  const int* dst = (const int*)d_in[2];
  const float* wl1 = (const float*)d_in[4];
  const float* wr1 = (const float*)d_in[5];
  const float* b1 = (const float*)d_in[6];
  const float* wl2 = (const float*)d_in[7];
  const float* wr2 = (const float*)d_in[8];
  const float* b2 = (const float*)d_in[9];
  const float* wl3 = (const float*)d_in[10];
  const float* wr3 = (const float*)d_in[11];
  const float* b3 = (const float*)d_in[12];
  const float* cw = (const float*)d_in[13];
  const float* cb = (const float*)d_in[14];
  const float* w1 = (const float*)d_in[15];
  const float* bb1 = (const float*)d_in[16];
  const float* w2 = (const float*)d_in[17];
  const float* bb2 = (const float*)d_in[18];
  float* out = (float*)d_out;

  char* w = (char*)d_ws;
  auto carve = [&](size_t bytes) {
    char* p = w;
    w += (bytes + 255) & ~(size_t)255;
    return p;
  };
  int* cnt = (int*)carve((size_t)NN * 4);
  int* row_start = (int*)carve((size_t)NN * 4);
  int* cursor = (int*)carve((size_t)NN * 4);
  int* eidx = (int*)carve((size_t)EE * 4);
  float* P = (float*)carve((size_t)NN * 64 * 4);
  float* R = (float*)carve((size_t)NN * 64 * 4);
  float* hbuf = (float*)carve((size_t)NN * 64 * 4);
  int* blockSum = (int*)carve((size_t)SCAN_BLOCKS * 4);

  zero_int<<<(NN + 1023) / 1024, 1024, 0, stream>>>(cnt, NN);
  count_kernel<<<2048, 256, 0, stream>>>(dst, cnt);
  scan_pass1<<<SCAN_BLOCKS, 256, 0, stream>>>(cnt, blockSum);
  scan_pass2<<<1, 128, 0, stream>>>(blockSum);
  scan_pass3<<<SCAN_BLOCKS, 256, 0, stream>>>(cnt, blockSum, row_start, cursor);
  fill_kernel<<<2048, 256, 0, stream>>>(src, dst, cursor, eidx);

  const int projGrid = (NN + 63) / 64;
  const int aggGrid = (NN + 3) / 4;
  proj_kernel<128><<<projGrid, 256, 0, stream>>>(x, wl1, wr1, P, R);
  agg_kernel<<<aggGrid, 256, 0, stream>>>(P, R, b1, row_start, cnt, eidx, hbuf);
  proj_kernel<64><<<projGrid, 256, 0, stream>>>(hbuf, wl2, wr2, P, R);
  agg_kernel<<<aggGrid, 256, 0, stream>>>(P, R, b2, row_start, cnt, eidx, hbuf);
  proj_kernel<64><<<projGrid, 256, 0, stream>>>(hbuf, wl3, wr3, P, R);
  agg_kernel<<<aggGrid, 256, 0, stream>>>(P, R, b3, row_start, cnt, eidx, hbuf);
  head_kernel<<<GG, 128, 0, stream>>>(hbuf, cw, cb, w1, bb1, w2, bb2, out);
}

// Round 3
// 595.305 us; speedup vs baseline: 1.5657x; 1.2091x over previous
//
#include <hip/hip_runtime.h>

#define NN 100000
#define EE 1600000
#define GG 1000
#define PERG 100
#define KK 30
#define HH 64

#define NB 782      // buckets of 128 nodes: 782*128 = 100096 >= NN
#define CAP 4096    // max edges/bucket (mean 2048, sigma ~45 -> huge margin)
#define CHB 16384   // edges per bucket_kernel block

__global__ __launch_bounds__(1024) void zero_int(int* p, int n) {
  int i = blockIdx.x * 1024 + threadIdx.x;
  if (i < n) p[i] = 0;
}

// Phase B: bucket edges by dst>>7 with LDS histograms + per-(block,bucket) run
// reservation. Writes are runs of ~21 consecutive packed entries -> no
// line-level write amplification (vs 102MB of scattered-atomic writeback).
__global__ __launch_bounds__(256) void bucket_kernel(const int* __restrict__ src,
                                                     const int* __restrict__ dst,
                                                     int* __restrict__ gcur,
                                                     int* __restrict__ pairs) {
  __shared__ int lhist[NB];
  __shared__ int lbase[NB];
  __shared__ int lcur[NB];
  const int t = threadIdx.x;
  const int c0 = blockIdx.x * CHB;
  const int c1 = min(c0 + CHB, EE);
  for (int b = t; b < NB; b += 256) {
    lhist[b] = 0;
    lcur[b] = 0;
  }
  __syncthreads();
  for (int e = c0 + t; e < c1; e += 256) atomicAdd(&lhist[dst[e] >> 7], 1);
  __syncthreads();
  for (int b = t; b < NB; b += 256) {
    int c = lhist[b];
    lbase[b] = c ? atomicAdd(&gcur[b], c) : 0;
  }
  __syncthreads();
  for (int e = c0 + t; e < c1; e += 256) {
    int d = dst[e];
    int b = d >> 7;
    int p = atomicAdd(&lcur[b], 1);
    pairs[b * CAP + lbase[b] + p] = (src[e] << 7) | (d & 127);
  }
}

// exclusive scan of 782 bucket counts -> global CSR base per bucket
__global__ __launch_bounds__(1024) void bucket_scan(const int* __restrict__ gcur,
                                                    int* __restrict__ bbase) {
  __shared__ int tmp[1024];
  const int t = threadIdx.x;
  int v = (t < NB) ? gcur[t] : 0;
  tmp[t] = v;
  __syncthreads();
  for (int off = 1; off < 1024; off <<= 1) {
    int u = (t >= off) ? tmp[t - off] : 0;
    __syncthreads();
    tmp[t] += u;
    __syncthreads();
  }
  if (t < NB) bbase[t] = tmp[t] - v;
}

// Phase C: one block per bucket; 128-bin LDS counting sort -> row_start/cnt/eidx.
// All writes are to this bucket's own contiguous regions (single XCD, coalesced).
__global__ __launch_bounds__(256) void csr_kernel(const int* __restrict__ gcur,
                                                  const int* __restrict__ bbase,
                                                  const int* __restrict__ pairs,
                                                  int* __restrict__ row_start,
                                                  int* __restrict__ cnt,
                                                  int* __restrict__ eidx) {
  __shared__ int vals[CAP];
  __shared__ int hist[128];
  __shared__ int offs[128];
  __shared__ int cur[128];
  const int b = blockIdx.x;
  const int t = threadIdx.x;
  const int nb = gcur[b];
  const int base = bbase[b];
  if (t < 128) {
    hist[t] = 0;
    cur[t] = 0;
  }
  __syncthreads();
  for (int i = t; i < nb; i += 256) {
    int v = pairs[b * CAP + i];
    vals[i] = v;
    atomicAdd(&hist[v & 127], 1);
  }
  __syncthreads();
  if (t < 128) {
    int s = 0;
    for (int m = 0; m < t; ++m) s += hist[m];
    offs[t] = s;
    int node = b * 128 + t;
    if (node < NN) {
      row_start[node] = base + s;
      cnt[node] = hist[t];
    }
  }
  __syncthreads();
  for (int i = t; i < nb; i += 256) {
    int v = vals[i];
    int ld = v & 127;
    int p = atomicAdd(&cur[ld], 1);
    eidx[base + offs[ld] + p] = v >> 7;
  }
}

// X [NN,K] @ (WL[K,64] | WR[K,64]) -> P [NN,64], R [NN,64]
template <int K>
__global__ __launch_bounds__(256) void proj_kernel(const float* __restrict__ X,
                                                   const float* __restrict__ WL,
                                                   const float* __restrict__ WR,
                                                   float* __restrict__ P,
                                                   float* __restrict__ R) {
  constexpr int BM = 64, BMP = 68, WSP = 144, BK = 32;
  __shared__ float xs[K * BMP];   // transposed x tile [k][row]
  __shared__ float ws[BK * WSP];  // swizzled W chunk [k][col-group swizzle]
  const int t = threadIdx.x;
  const int row0 = blockIdx.x * BM;
  constexpr int KQ = K / 4;

  // stage X transposed (coalesced float4 global reads)
  for (int idx = t; idx < BM * KQ; idx += 256) {
    int r = idx / KQ, kq = idx % KQ;
    int row = row0 + r;
    float4 v = make_float4(0.f, 0.f, 0.f, 0.f);
    if (row < NN) v = *reinterpret_cast<const float4*>(&X[(size_t)row * K + kq * 4]);
    xs[(kq * 4 + 0) * BMP + r] = v.x;
    xs[(kq * 4 + 1) * BMP + r] = v.y;
    xs[(kq * 4 + 2) * BMP + r] = v.z;
    xs[(kq * 4 + 3) * BMP + r] = v.w;
  }

  const int tc = t & 15, tr = t >> 4;
  const int wcol = tc * 8 + (tc >> 2) * 4;  // swizzled column offset (<=2-way banks)
  float acc[4][8];
#pragma unroll
  for (int i = 0; i < 4; ++i)
#pragma unroll
    for (int j = 0; j < 8; ++j) acc[i][j] = 0.f;

  for (int k0 = 0; k0 < K; k0 += BK) {
    __syncthreads();
    // stage W chunk (both WL and WR) with swizzle
    for (int idx = t; idx < BK * 16; idx += 256) {
      int kr = idx >> 4, c4 = idx & 15;
      int gcl = c4 >> 1;
      int off = gcl * 8 + (gcl >> 2) * 4 + (c4 & 1) * 4;
      *reinterpret_cast<float4*>(&ws[kr * WSP + off]) =
          *reinterpret_cast<const float4*>(&WL[(k0 + kr) * 64 + c4 * 4]);
      int g2 = gcl + 8;
      int off2 = g2 * 8 + (g2 >> 2) * 4 + (c4 & 1) * 4;
      *reinterpret_cast<float4*>(&ws[kr * WSP + off2]) =
          *reinterpret_cast<const float4*>(&WR[(k0 + kr) * 64 + c4 * 4]);
    }
    __syncthreads();
#pragma unroll 4
    for (int kk = 0; kk < BK; ++kk) {
      int k = k0 + kk;
      float4 a4 = *reinterpret_cast<const float4*>(&xs[k * BMP + tr * 4]);
      float4 b04 = *reinterpret_cast<const float4*>(&ws[kk * WSP + wcol]);
      float4 b14 = *reinterpret_cast<const float4*>(&ws[kk * WSP + wcol + 4]);
      float av[4] = {a4.x, a4.y, a4.z, a4.w};
      float bv[8] = {b04.x, b04.y, b04.z, b04.w, b14.x, b14.y, b14.z, b14.w};
#pragma unroll
      for (int i = 0; i < 4; ++i)
#pragma unroll
        for (int j = 0; j < 8; ++j) acc[i][j] = fmaf(av[i], bv[j], acc[i][j]);
    }
  }

  float* OUT = (tc < 8) ? P : R;
  int cb = (tc & 7) * 8;
#pragma unroll
  for (int i = 0; i < 4; ++i) {
    int row = row0 + tr * 4 + i;
    if (row < NN) {
      float4 lo = make_float4(acc[i][0], acc[i][1], acc[i][2], acc[i][3]);
      float4 hi = make_float4(acc[i][4], acc[i][5], acc[i][6], acc[i][7]);
      *reinterpret_cast<float4*>(&OUT[(size_t)row * 64 + cb]) = lo;
      *reinterpret_cast<float4*>(&OUT[(size_t)row * 64 + cb + 4]) = hi;
    }
  }
}

// one wave per node: h[i] = relu(mean_j P[src_j] + b + R[i])
__global__ __launch_bounds__(256) void agg_kernel(const float* __restrict__ P,
                                                  const float* __restrict__ R,
                                                  const float* __restrict__ bias,
                                                  const int* __restrict__ row_start,
                                                  const int* __restrict__ cnt,
                                                  const int* __restrict__ eidx,
                                                  float* __restrict__ h) {
  int wid = (blockIdx.x * 256 + threadIdx.x) >> 6;
  int lane = threadIdx.x & 63;
  if (wid >= NN) return;
  int base = row_start[wid];
  int deg = cnt[wid];
  float acc0 = 0.f, acc1 = 0.f;
  for (int e0 = 0; e0 < deg; e0 += 64) {
    int m = min(64, deg - e0);
    int idx = (lane < m) ? eidx[base + e0 + lane] : 0;
    int j = 0;
    for (; j + 1 < m; j += 2) {
      int s0 = __shfl(idx, j);
      int s1 = __shfl(idx, j + 1);
      acc0 += P[(size_t)s0 * 64 + lane];
      acc1 += P[(size_t)s1 * 64 + lane];
    }
    if (j < m) {
      int s0 = __shfl(idx, j);
      acc0 += P[(size_t)s0 * 64 + lane];
    }
  }
  float mean = (acc0 + acc1) / fmaxf((float)deg, 1.0f);
  h[(size_t)wid * 64 + lane] = fmaxf(mean + bias[lane] + R[(size_t)wid * 64 + lane], 0.0f);
}

// one block per graph: stable top-30 by last channel, conv1d, MLP head
__global__ __launch_bounds__(128) void head_kernel(const float* __restrict__ h,
                                                   const float* __restrict__ cw,
                                                   const float* __restrict__ cb,
                                                   const float* __restrict__ w1,
                                                   const float* __restrict__ bb1,
                                                   const float* __restrict__ w2,
                                                   const float* __restrict__ bb2,
                                                   float* __restrict__ out) {
  __shared__ float key[PERG];
  __shared__ int sel[KK];
  __shared__ float feat[KK][65];
  __shared__ float cws[32 * 192];
  __shared__ float z[896];
  __shared__ float psum[128];
  const int g = blockIdx.x;
  const int t = threadIdx.x;

  for (int idx = t; idx < 32 * 192; idx += 128) cws[idx] = cw[idx];
  if (t < PERG) key[t] = h[(size_t)(g * PERG + t) * HH + (HH - 1)];
  __syncthreads();

  if (t < PERG) {
    float kv = key[t];
    int r = 0;
    for (int m = 0; m < PERG; ++m) {
      float km = key[m];
      r += (int)((km > kv) || (km == kv && m < t));
    }
    if (r < KK) sel[r] = t;
  }
  __syncthreads();

  for (int idx = t; idx < KK * HH; idx += 128) {
    int r = idx >> 6, f = idx & 63;
    feat[r][f] = h[(size_t)(g * PERG + sel[r]) * HH + f];
  }
  __syncthreads();

  for (int idx = t; idx < 32 * 28; idx += 128) {
    int o = idx / 28, p = idx % 28;
    float acc = cb[o];
#pragma unroll
    for (int tt = 0; tt < 3; ++tt)
      for (int i = 0; i < 64; ++i)
        acc = fmaf(feat[p + tt][i], cws[o * 192 + i * 3 + tt], acc);
    z[o * 28 + p] = fmaxf(acc, 0.f);
  }
  __syncthreads();

  {
    int hh = t & 63, half = t >> 6;
    int q0 = half * 448;
    float acc = 0.f;
    for (int q = 0; q < 448; ++q) acc = fmaf(z[q0 + q], w1[(q0 + q) * 64 + hh], acc);
    psum[t] = acc;
  }
  __syncthreads();

  if (t < 64) {
    float o1 = fmaxf(bb1[t] + psum[t] + psum[t + 64], 0.f);
    float v = o1 * w2[t];
#pragma unroll
    for (int off = 32; off > 0; off >>= 1) v += __shfl_down(v, off);
    if (t == 0) out[g] = v + bb2[0];
  }
}

extern "C" void kernel_launch(void* const* d_in, const int* in_sizes, int n_in,
                              void* d_out, int out_size, void* d_ws, size_t ws_size,
                              hipStream_t stream) {
  const float* x = (const float*)d_in[0];
  const int* src = (const int*)d_in[1];
  const int* dst = (const int*)d_in[2];
  const float* wl1 = (const float*)d_in[4];
  const float* wr1 = (const float*)d_in[5];
  const float* b1 = (const float*)d_in[6];
  const float* wl2 = (const float*)d_in[7];
  const float* wr2 = (const float*)d_in[8];
  const float* b2 = (const float*)d_in[9];
  const float* wl3 = (const float*)d_in[10];
  const float* wr3 = (const float*)d_in[11];
  const float* b3 = (const float*)d_in[12];
  const float* cw = (const float*)d_in[13];
  const float* cb = (const float*)d_in[14];
  const float* w1 = (const float*)d_in[15];
  const float* bb1 = (const float*)d_in[16];
  const float* w2 = (const float*)d_in[17];
  const float* bb2 = (const float*)d_in[18];
  float* out = (float*)d_out;

  char* w = (char*)d_ws;
  auto carve = [&](size_t bytes) {
    char* p = w;
    w += (bytes + 255) & ~(size_t)255;
    return p;
  };
  int* row_start = (int*)carve((size_t)NN * 4);
  int* cnt = (int*)carve((size_t)NN * 4);
  int* eidx = (int*)carve((size_t)EE * 4);
  float* P = (float*)carve((size_t)NN * 64 * 4);
  float* R = (float*)carve((size_t)NN * 64 * 4);
  float* hbuf = (float*)carve((size_t)NN * 64 * 4);
  int* gcur = (int*)carve((size_t)NB * 4);
  int* bbase = (int*)carve((size_t)NB * 4);
  // pairs aliases P: csr_kernel finishes reading it (stream order) before
  // proj_kernel<128> writes P.
  int* pairs = (int*)P;  // NB*CAP*4 = 12.8 MB < 25.6 MB

  zero_int<<<1, 1024, 0, stream>>>(gcur, NB);
  bucket_kernel<<<(EE + CHB - 1) / CHB, 256, 0, stream>>>(src, dst, gcur, pairs);
  bucket_scan<<<1, 1024, 0, stream>>>(gcur, bbase);
  csr_kernel<<<NB, 256, 0, stream>>>(gcur, bbase, pairs, row_start, cnt, eidx);

  const int projGrid = (NN + 63) / 64;
  const int aggGrid = (NN + 3) / 4;
  proj_kernel<128><<<projGrid, 256, 0, stream>>>(x, wl1, wr1, P, R);
  agg_kernel<<<aggGrid, 256, 0, stream>>>(P, R, b1, row_start, cnt, eidx, hbuf);
  proj_kernel<64><<<projGrid, 256, 0, stream>>>(hbuf, wl2, wr2, P, R);
  agg_kernel<<<aggGrid, 256, 0, stream>>>(P, R, b2, row_start, cnt, eidx, hbuf);
  proj_kernel<64><<<projGrid, 256, 0, stream>>>(hbuf, wl3, wr3, P, R);
  agg_kernel<<<aggGrid, 256, 0, stream>>>(P, R, b3, row_start, cnt, eidx, hbuf);
  head_kernel<<<GG, 128, 0, stream>>>(hbuf, cw, cb, w1, bb1, w2, bb2, out);
}

// Round 4
// 527.558 us; speedup vs baseline: 1.7667x; 1.1284x over previous
//
#include <hip/hip_runtime.h>

#define NN 100000
#define EE 1600000
#define GG 1000
#define PERG 100
#define KK 30
#define HH 64

#define NB 782      // buckets of 128 nodes: 782*128 = 100096 >= NN
#define CAP 4096    // max edges/bucket (mean 2048, sigma ~45 -> huge margin)
#define CHB 4096    // edges per bucket_kernel block -> 391 blocks (~6 waves/CU)

__global__ __launch_bounds__(1024) void zero_int(int* p, int n) {
  int i = blockIdx.x * 1024 + threadIdx.x;
  if (i < n) p[i] = 0;
}

// Phase B: bucket edges by dst>>7 with LDS histograms + per-(block,bucket) run
// reservation. Runs of ~5 consecutive packed entries -> small write
// amplification, high block-level parallelism.
__global__ __launch_bounds__(256) void bucket_kernel(const int* __restrict__ src,
                                                     const int* __restrict__ dst,
                                                     int* __restrict__ gcur,
                                                     int* __restrict__ pairs) {
  __shared__ int lhist[NB];
  __shared__ int lbase[NB];
  __shared__ int lcur[NB];
  const int t = threadIdx.x;
  const int c0 = blockIdx.x * CHB;
  const int c1 = min(c0 + CHB, EE);
  for (int b = t; b < NB; b += 256) {
    lhist[b] = 0;
    lcur[b] = 0;
  }
  __syncthreads();
  for (int e = c0 + t; e < c1; e += 256) atomicAdd(&lhist[dst[e] >> 7], 1);
  __syncthreads();
  for (int b = t; b < NB; b += 256) {
    int c = lhist[b];
    lbase[b] = c ? atomicAdd(&gcur[b], c) : 0;
  }
  __syncthreads();
  for (int e = c0 + t; e < c1; e += 256) {
    int d = dst[e];
    int b = d >> 7;
    int p = atomicAdd(&lcur[b], 1);
    pairs[b * CAP + lbase[b] + p] = (src[e] << 7) | (d & 127);
  }
}

// exclusive scan of 782 bucket counts -> global CSR base per bucket
__global__ __launch_bounds__(1024) void bucket_scan(const int* __restrict__ gcur,
                                                    int* __restrict__ bbase) {
  __shared__ int tmp[1024];
  const int t = threadIdx.x;
  int v = (t < NB) ? gcur[t] : 0;
  tmp[t] = v;
  __syncthreads();
  for (int off = 1; off < 1024; off <<= 1) {
    int u = (t >= off) ? tmp[t - off] : 0;
    __syncthreads();
    tmp[t] += u;
    __syncthreads();
  }
  if (t < NB) bbase[t] = tmp[t] - v;
}

// Phase C: one block per bucket; 128-bin LDS counting sort -> row_start/cnt/eidx.
__global__ __launch_bounds__(256) void csr_kernel(const int* __restrict__ gcur,
                                                  const int* __restrict__ bbase,
                                                  const int* __restrict__ pairs,
                                                  int* __restrict__ row_start,
                                                  int* __restrict__ cnt,
                                                  int* __restrict__ eidx) {
  __shared__ int vals[CAP];
  __shared__ int hist[128];
  __shared__ int offs[128];
  __shared__ int cur[128];
  const int b = blockIdx.x;
  const int t = threadIdx.x;
  const int nb = gcur[b];
  const int base = bbase[b];
  if (t < 128) {
    hist[t] = 0;
    cur[t] = 0;
  }
  __syncthreads();
  for (int i = t; i < nb; i += 256) {
    int v = pairs[b * CAP + i];
    vals[i] = v;
    atomicAdd(&hist[v & 127], 1);
  }
  __syncthreads();
  if (t < 128) {
    int s = 0;
    for (int m = 0; m < t; ++m) s += hist[m];
    offs[t] = s;
    int node = b * 128 + t;
    if (node < NN) {
      row_start[node] = base + s;
      cnt[node] = hist[t];
    }
  }
  __syncthreads();
  for (int i = t; i < nb; i += 256) {
    int v = vals[i];
    int ld = v & 127;
    int p = atomicAdd(&cur[ld], 1);
    eidx[base + offs[ld] + p] = v >> 7;
  }
}

// X [NN,K] @ (WL[K,64] | WR[K,64]) -> P [NN,64], R [NN,64]
template <int K>
__global__ __launch_bounds__(256) void proj_kernel(const float* __restrict__ X,
                                                   const float* __restrict__ WL,
                                                   const float* __restrict__ WR,
                                                   float* __restrict__ P,
                                                   float* __restrict__ R) {
  constexpr int BM = 64, BMP = 68, WSP = 144, BK = 32;
  __shared__ float xs[K * BMP];   // transposed x tile [k][row]
  __shared__ float ws[BK * WSP];  // swizzled W chunk [k][col-group swizzle]
  const int t = threadIdx.x;
  const int row0 = blockIdx.x * BM;
  constexpr int KQ = K / 4;

  for (int idx = t; idx < BM * KQ; idx += 256) {
    int r = idx / KQ, kq = idx % KQ;
    int row = row0 + r;
    float4 v = make_float4(0.f, 0.f, 0.f, 0.f);
    if (row < NN) v = *reinterpret_cast<const float4*>(&X[(size_t)row * K + kq * 4]);
    xs[(kq * 4 + 0) * BMP + r] = v.x;
    xs[(kq * 4 + 1) * BMP + r] = v.y;
    xs[(kq * 4 + 2) * BMP + r] = v.z;
    xs[(kq * 4 + 3) * BMP + r] = v.w;
  }

  const int tc = t & 15, tr = t >> 4;
  const int wcol = tc * 8 + (tc >> 2) * 4;  // swizzled column offset (<=2-way banks)
  float acc[4][8];
#pragma unroll
  for (int i = 0; i < 4; ++i)
#pragma unroll
    for (int j = 0; j < 8; ++j) acc[i][j] = 0.f;

  for (int k0 = 0; k0 < K; k0 += BK) {
    __syncthreads();
    for (int idx = t; idx < BK * 16; idx += 256) {
      int kr = idx >> 4, c4 = idx & 15;
      int gcl = c4 >> 1;
      int off = gcl * 8 + (gcl >> 2) * 4 + (c4 & 1) * 4;
      *reinterpret_cast<float4*>(&ws[kr * WSP + off]) =
          *reinterpret_cast<const float4*>(&WL[(k0 + kr) * 64 + c4 * 4]);
      int g2 = gcl + 8;
      int off2 = g2 * 8 + (g2 >> 2) * 4 + (c4 & 1) * 4;
      *reinterpret_cast<float4*>(&ws[kr * WSP + off2]) =
          *reinterpret_cast<const float4*>(&WR[(k0 + kr) * 64 + c4 * 4]);
    }
    __syncthreads();
#pragma unroll 4
    for (int kk = 0; kk < BK; ++kk) {
      int k = k0 + kk;
      float4 a4 = *reinterpret_cast<const float4*>(&xs[k * BMP + tr * 4]);
      float4 b04 = *reinterpret_cast<const float4*>(&ws[kk * WSP + wcol]);
      float4 b14 = *reinterpret_cast<const float4*>(&ws[kk * WSP + wcol + 4]);
      float av[4] = {a4.x, a4.y, a4.z, a4.w};
      float bv[8] = {b04.x, b04.y, b04.z, b04.w, b14.x, b14.y, b14.z, b14.w};
#pragma unroll
      for (int i = 0; i < 4; ++i)
#pragma unroll
        for (int j = 0; j < 8; ++j) acc[i][j] = fmaf(av[i], bv[j], acc[i][j]);
    }
  }

  float* OUT = (tc < 8) ? P : R;
  int cb = (tc & 7) * 8;
#pragma unroll
  for (int i = 0; i < 4; ++i) {
    int row = row0 + tr * 4 + i;
    if (row < NN) {
      float4 lo = make_float4(acc[i][0], acc[i][1], acc[i][2], acc[i][3]);
      float4 hi = make_float4(acc[i][4], acc[i][5], acc[i][6], acc[i][7]);
      *reinterpret_cast<float4*>(&OUT[(size_t)row * 64 + cb]) = lo;
      *reinterpret_cast<float4*>(&OUT[(size_t)row * 64 + cb + 4]) = hi;
    }
  }
}

// one wave per node: h[i] = relu(mean_j P[src_j] + b + R[i]).
// keys (optional): lane 63 writes the sort key compactly for the head.
__global__ __launch_bounds__(256) void agg_kernel(const float* __restrict__ P,
                                                  const float* __restrict__ R,
                                                  const float* __restrict__ bias,
                                                  const int* __restrict__ row_start,
                                                  const int* __restrict__ cnt,
                                                  const int* __restrict__ eidx,
                                                  float* __restrict__ h,
                                                  float* __restrict__ keys) {
  int wid = (blockIdx.x * 256 + threadIdx.x) >> 6;
  int lane = threadIdx.x & 63;
  if (wid >= NN) return;
  int base = row_start[wid];
  int deg = cnt[wid];
  float acc0 = 0.f, acc1 = 0.f;
  for (int e0 = 0; e0 < deg; e0 += 64) {
    int m = min(64, deg - e0);
    int idx = (lane < m) ? eidx[base + e0 + lane] : 0;
    int j = 0;
    for (; j + 1 < m; j += 2) {
      int s0 = __shfl(idx, j);
      int s1 = __shfl(idx, j + 1);
      acc0 += P[(size_t)s0 * 64 + lane];
      acc1 += P[(size_t)s1 * 64 + lane];
    }
    if (j < m) {
      int s0 = __shfl(idx, j);
      acc0 += P[(size_t)s0 * 64 + lane];
    }
  }
  float mean = (acc0 + acc1) / fmaxf((float)deg, 1.0f);
  float val = fmaxf(mean + bias[lane] + R[(size_t)wid * 64 + lane], 0.0f);
  h[(size_t)wid * 64 + lane] = val;
  if (keys != nullptr && lane == 63) keys[wid] = val;
}

// one block (256 thr) per graph: stable top-30, conv1d (conflict-free weights),
// MLP head. Keys come from the compact keys[] array (coalesced).
__global__ __launch_bounds__(256) void head_kernel(const float* __restrict__ h,
                                                   const float* __restrict__ keysArr,
                                                   const float* __restrict__ cw,
                                                   const float* __restrict__ cb,
                                                   const float* __restrict__ w1,
                                                   const float* __restrict__ bb1,
                                                   const float* __restrict__ w2,
                                                   const float* __restrict__ bb2,
                                                   float* __restrict__ out) {
  __shared__ float key[PERG];
  __shared__ int sel[KK];
  __shared__ float feat[34 * 65];   // rows 30..33 garbage-read only by dead lanes
  __shared__ float cwT[192 * 33];   // [k][o] padded: conflict-free stage + read
  __shared__ float z[896];          // conv output, flat q = o*28+p
  __shared__ float psum[256];
  const int g = blockIdx.x;
  const int t = threadIdx.x;

  // stage transposed conv weights: cwT[k*33+o] = cw[o*192+k] (coalesced read,
  // conflict-free LDS write since (k*33+o)%32 = (k+o)%32 with k consecutive)
  for (int idx = t; idx < 32 * 192; idx += 256) {
    int o = idx / 192, k = idx % 192;
    cwT[k * 33 + o] = cw[idx];
  }
  if (t < PERG) key[t] = keysArr[g * PERG + t];
  __syncthreads();

  // stable descending rank by key, tie -> lower index first
  if (t < PERG) {
    float kv = key[t];
    int r = 0;
    for (int m = 0; m < PERG; ++m) {
      float km = key[m];
      r += (int)((km > kv) || (km == kv && m < t));
    }
    if (r < KK) sel[r] = t;
  }
  __syncthreads();

  // gather top-30 feature rows
  for (int idx = t; idx < KK * HH; idx += 256) {
    int r = idx >> 6, f = idx & 63;
    feat[r * 65 + f] = h[(size_t)(g * PERG + sel[r]) * HH + f];
  }
  __syncthreads();

  // conv1d: z[o, p] = relu(cb[o] + sum_{i,tt} feat[p+tt][i] * cw[o][i][tt])
  // lanes: o = t&31 (cwT reads conflict-free), 8 p-groups, 4 p each
  {
    const int o = t & 31;
    const int pg = t >> 5;  // 0..7
    float zacc[4] = {0.f, 0.f, 0.f, 0.f};
    int i = 0, tt = 0;
    for (int k = 0; k < 192; ++k) {
      float c = cwT[k * 33 + o];
#pragma unroll
      for (int j = 0; j < 4; ++j) {
        int p = pg + 8 * j;  // may be >=28 for some lanes: reads garbage rows,
        zacc[j] = fmaf(c, feat[(p + tt) * 65 + i], zacc[j]);  // never stored
      }
      if (++tt == 3) {
        tt = 0;
        ++i;
      }
    }
    float cbo = cb[o];
#pragma unroll
    for (int j = 0; j < 4; ++j) {
      int p = pg + 8 * j;
      if (p < 28) z[o * 28 + p] = fmaxf(zacc[j] + cbo, 0.f);
    }
  }
  __syncthreads();

  // o1 = relu(z @ w1 + bb1): 4 waves each cover 224 of K=896; h-dim in lanes
  {
    const int hh = t & 63;
    const int quarter = t >> 6;
    const int q0 = quarter * 224;
    float acc = 0.f;
    for (int q = 0; q < 224; ++q)
      acc = fmaf(z[q0 + q], w1[(size_t)(q0 + q) * 64 + hh], acc);
    psum[t] = acc;
  }
  __syncthreads();

  if (t < 64) {
    float o1 = fmaxf(bb1[t] + psum[t] + psum[t + 64] + psum[t + 128] + psum[t + 192], 0.f);
    float v = o1 * w2[t];
#pragma unroll
    for (int off = 32; off > 0; off >>= 1) v += __shfl_down(v, off);
    if (t == 0) out[g] = v + bb2[0];
  }
}

extern "C" void kernel_launch(void* const* d_in, const int* in_sizes, int n_in,
                              void* d_out, int out_size, void* d_ws, size_t ws_size,
                              hipStream_t stream) {
  const float* x = (const float*)d_in[0];
  const int* src = (const int*)d_in[1];
  const int* dst = (const int*)d_in[2];
  const float* wl1 = (const float*)d_in[4];
  const float* wr1 = (const float*)d_in[5];
  const float* b1 = (const float*)d_in[6];
  const float* wl2 = (const float*)d_in[7];
  const float* wr2 = (const float*)d_in[8];
  const float* b2 = (const float*)d_in[9];
  const float* wl3 = (const float*)d_in[10];
  const float* wr3 = (const float*)d_in[11];
  const float* b3 = (const float*)d_in[12];
  const float* cw = (const float*)d_in[13];
  const float* cb = (const float*)d_in[14];
  const float* w1 = (const float*)d_in[15];
  const float* bb1 = (const float*)d_in[16];
  const float* w2 = (const float*)d_in[17];
  const float* bb2 = (const float*)d_in[18];
  float* out = (float*)d_out;

  char* w = (char*)d_ws;
  auto carve = [&](size_t bytes) {
    char* p = w;
    w += (bytes + 255) & ~(size_t)255;
    return p;
  };
  int* row_start = (int*)carve((size_t)NN * 4);
  int* cnt = (int*)carve((size_t)NN * 4);
  int* eidx = (int*)carve((size_t)EE * 4);
  float* P = (float*)carve((size_t)NN * 64 * 4);
  float* R = (float*)carve((size_t)NN * 64 * 4);
  float* hbuf = (float*)carve((size_t)NN * 64 * 4);
  float* keys = (float*)carve((size_t)NN * 4);
  int* gcur = (int*)carve((size_t)NB * 4);
  int* bbase = (int*)carve((size_t)NB * 4);
  // pairs aliases P: csr_kernel finishes reading it (stream order) before
  // proj_kernel<128> writes P.
  int* pairs = (int*)P;  // NB*CAP*4 = 12.8 MB < 25.6 MB

  zero_int<<<1, 1024, 0, stream>>>(gcur, NB);
  bucket_kernel<<<(EE + CHB - 1) / CHB, 256, 0, stream>>>(src, dst, gcur, pairs);
  bucket_scan<<<1, 1024, 0, stream>>>(gcur, bbase);
  csr_kernel<<<NB, 256, 0, stream>>>(gcur, bbase, pairs, row_start, cnt, eidx);

  const int projGrid = (NN + 63) / 64;
  const int aggGrid = (NN + 3) / 4;
  proj_kernel<128><<<projGrid, 256, 0, stream>>>(x, wl1, wr1, P, R);
  agg_kernel<<<aggGrid, 256, 0, stream>>>(P, R, b1, row_start, cnt, eidx, hbuf, nullptr);
  proj_kernel<64><<<projGrid, 256, 0, stream>>>(hbuf, wl2, wr2, P, R);
  agg_kernel<<<aggGrid, 256, 0, stream>>>(P, R, b2, row_start, cnt, eidx, hbuf, nullptr);
  proj_kernel<64><<<projGrid, 256, 0, stream>>>(hbuf, wl3, wr3, P, R);
  agg_kernel<<<aggGrid, 256, 0, stream>>>(P, R, b3, row_start, cnt, eidx, hbuf, keys);
  head_kernel<<<GG, 256, 0, stream>>>(hbuf, keys, cw, cb, w1, bb1, w2, bb2, out);
}

// Round 5
// 483.705 us; speedup vs baseline: 1.9269x; 1.0907x over previous
//
#include <hip/hip_runtime.h>

#define NN 100000
#define EE 1600000
#define GG 1000
#define PERG 100
#define KK 30
#define HH 64

#define NB 782      // buckets of 128 nodes: 782*128 = 100096 >= NN
#define CAP 4096    // max edges/bucket (mean 2048, sigma ~45 -> huge margin)
#define CHB 4096    // edges per bucket_kernel block -> 391 blocks (~6 waves/CU)

__global__ __launch_bounds__(1024) void zero_int(int* p, int n) {
  int i = blockIdx.x * 1024 + threadIdx.x;
  if (i < n) p[i] = 0;
}

// Phase B: bucket edges by dst>>7 with LDS histograms + per-(block,bucket) run
// reservation.
__global__ __launch_bounds__(256) void bucket_kernel(const int* __restrict__ src,
                                                     const int* __restrict__ dst,
                                                     int* __restrict__ gcur,
                                                     int* __restrict__ pairs) {
  __shared__ int lhist[NB];
  __shared__ int lbase[NB];
  __shared__ int lcur[NB];
  const int t = threadIdx.x;
  const int c0 = blockIdx.x * CHB;
  const int c1 = min(c0 + CHB, EE);
  for (int b = t; b < NB; b += 256) {
    lhist[b] = 0;
    lcur[b] = 0;
  }
  __syncthreads();
  for (int e = c0 + t; e < c1; e += 256) atomicAdd(&lhist[dst[e] >> 7], 1);
  __syncthreads();
  for (int b = t; b < NB; b += 256) {
    int c = lhist[b];
    lbase[b] = c ? atomicAdd(&gcur[b], c) : 0;
  }
  __syncthreads();
  for (int e = c0 + t; e < c1; e += 256) {
    int d = dst[e];
    int b = d >> 7;
    int p = atomicAdd(&lcur[b], 1);
    pairs[b * CAP + lbase[b] + p] = (src[e] << 7) | (d & 127);
  }
}

// exclusive scan of 782 bucket counts -> global CSR base per bucket
__global__ __launch_bounds__(1024) void bucket_scan(const int* __restrict__ gcur,
                                                    int* __restrict__ bbase) {
  __shared__ int tmp[1024];
  const int t = threadIdx.x;
  int v = (t < NB) ? gcur[t] : 0;
  tmp[t] = v;
  __syncthreads();
  for (int off = 1; off < 1024; off <<= 1) {
    int u = (t >= off) ? tmp[t - off] : 0;
    __syncthreads();
    tmp[t] += u;
    __syncthreads();
  }
  if (t < NB) bbase[t] = tmp[t] - v;
}

// Phase C: one block per bucket; 128-bin LDS counting sort -> row_start/cnt/eidx.
__global__ __launch_bounds__(256) void csr_kernel(const int* __restrict__ gcur,
                                                  const int* __restrict__ bbase,
                                                  const int* __restrict__ pairs,
                                                  int* __restrict__ row_start,
                                                  int* __restrict__ cnt,
                                                  int* __restrict__ eidx) {
  __shared__ int vals[CAP];
  __shared__ int hist[128];
  __shared__ int offs[128];
  __shared__ int cur[128];
  const int b = blockIdx.x;
  const int t = threadIdx.x;
  const int nb = gcur[b];
  const int base = bbase[b];
  if (t < 128) {
    hist[t] = 0;
    cur[t] = 0;
  }
  __syncthreads();
  for (int i = t; i < nb; i += 256) {
    int v = pairs[b * CAP + i];
    vals[i] = v;
    atomicAdd(&hist[v & 127], 1);
  }
  __syncthreads();
  if (t < 128) {
    int s = 0;
    for (int m = 0; m < t; ++m) s += hist[m];
    offs[t] = s;
    int node = b * 128 + t;
    if (node < NN) {
      row_start[node] = base + s;
      cnt[node] = hist[t];
    }
  }
  __syncthreads();
  for (int i = t; i < nb; i += 256) {
    int v = vals[i];
    int ld = v & 127;
    int p = atomicAdd(&cur[ld], 1);
    eidx[base + offs[ld] + p] = v >> 7;
  }
}

// X [NN,K] @ (WL[K,64] | WR[K,64]) -> P [NN,64], R [NN,64]
template <int K>
__global__ __launch_bounds__(256) void proj_kernel(const float* __restrict__ X,
                                                   const float* __restrict__ WL,
                                                   const float* __restrict__ WR,
                                                   float* __restrict__ P,
                                                   float* __restrict__ R) {
  constexpr int BM = 64, BMP = 68, WSP = 144, BK = 32;
  __shared__ float xs[K * BMP];   // transposed x tile [k][row]
  __shared__ float ws[BK * WSP];  // swizzled W chunk [k][col-group swizzle]
  const int t = threadIdx.x;
  const int row0 = blockIdx.x * BM;
  constexpr int KQ = K / 4;

  for (int idx = t; idx < BM * KQ; idx += 256) {
    int r = idx / KQ, kq = idx % KQ;
    int row = row0 + r;
    float4 v = make_float4(0.f, 0.f, 0.f, 0.f);
    if (row < NN) v = *reinterpret_cast<const float4*>(&X[(size_t)row * K + kq * 4]);
    xs[(kq * 4 + 0) * BMP + r] = v.x;
    xs[(kq * 4 + 1) * BMP + r] = v.y;
    xs[(kq * 4 + 2) * BMP + r] = v.z;
    xs[(kq * 4 + 3) * BMP + r] = v.w;
  }

  const int tc = t & 15, tr = t >> 4;
  const int wcol = tc * 8 + (tc >> 2) * 4;  // swizzled column offset (<=2-way banks)
  float acc[4][8];
#pragma unroll
  for (int i = 0; i < 4; ++i)
#pragma unroll
    for (int j = 0; j < 8; ++j) acc[i][j] = 0.f;

  for (int k0 = 0; k0 < K; k0 += BK) {
    __syncthreads();
    for (int idx = t; idx < BK * 16; idx += 256) {
      int kr = idx >> 4, c4 = idx & 15;
      int gcl = c4 >> 1;
      int off = gcl * 8 + (gcl >> 2) * 4 + (c4 & 1) * 4;
      *reinterpret_cast<float4*>(&ws[kr * WSP + off]) =
          *reinterpret_cast<const float4*>(&WL[(k0 + kr) * 64 + c4 * 4]);
      int g2 = gcl + 8;
      int off2 = g2 * 8 + (g2 >> 2) * 4 + (c4 & 1) * 4;
      *reinterpret_cast<float4*>(&ws[kr * WSP + off2]) =
          *reinterpret_cast<const float4*>(&WR[(k0 + kr) * 64 + c4 * 4]);
    }
    __syncthreads();
#pragma unroll 4
    for (int kk = 0; kk < BK; ++kk) {
      int k = k0 + kk;
      float4 a4 = *reinterpret_cast<const float4*>(&xs[k * BMP + tr * 4]);
      float4 b04 = *reinterpret_cast<const float4*>(&ws[kk * WSP + wcol]);
      float4 b14 = *reinterpret_cast<const float4*>(&ws[kk * WSP + wcol + 4]);
      float av[4] = {a4.x, a4.y, a4.z, a4.w};
      float bv[8] = {b04.x, b04.y, b04.z, b04.w, b14.x, b14.y, b14.z, b14.w};
#pragma unroll
      for (int i = 0; i < 4; ++i)
#pragma unroll
        for (int j = 0; j < 8; ++j) acc[i][j] = fmaf(av[i], bv[j], acc[i][j]);
    }
  }

  float* OUT = (tc < 8) ? P : R;
  int cb = (tc & 7) * 8;
#pragma unroll
  for (int i = 0; i < 4; ++i) {
    int row = row0 + tr * 4 + i;
    if (row < NN) {
      float4 lo = make_float4(acc[i][0], acc[i][1], acc[i][2], acc[i][3]);
      float4 hi = make_float4(acc[i][4], acc[i][5], acc[i][6], acc[i][7]);
      *reinterpret_cast<float4*>(&OUT[(size_t)row * 64 + cb]) = lo;
      *reinterpret_cast<float4*>(&OUT[(size_t)row * 64 + cb + 4]) = hi;
    }
  }
}

// one wave per node, quarter-wave per edge: 16 lanes x float4 = one 256B P row
// per quarter -> one dwordx4 instruction covers 4 edges; j-loop keeps 4 such
// loads in flight (16 edges). Validity via clamp + 0/1-weight fmaf (no exec
// churn). Cross-quarter shfl_xor reduction; quarter 0 does the epilogue.
__global__ __launch_bounds__(256) void agg_kernel(const float* __restrict__ P,
                                                  const float* __restrict__ R,
                                                  const float* __restrict__ bias,
                                                  const int* __restrict__ row_start,
                                                  const int* __restrict__ cnt,
                                                  const int* __restrict__ eidx,
                                                  float* __restrict__ h,
                                                  float* __restrict__ keys) {
  int wid = (blockIdx.x * 256 + threadIdx.x) >> 6;
  int lane = threadIdx.x & 63;
  if (wid >= NN) return;
  const int q = lane >> 4;   // quarter 0..3
  const int ql = lane & 15;  // lane within quarter -> features [ql*4, ql*4+4)
  const int base = row_start[wid];
  const int deg = cnt[wid];
  float4 a0 = make_float4(0.f, 0.f, 0.f, 0.f);
  float4 a1 = make_float4(0.f, 0.f, 0.f, 0.f);

  for (int e0 = 0; e0 < deg; e0 += 64) {
    const int m = min(64, deg - e0);
    int idx = (lane < m) ? eidx[base + e0 + lane] : 0;
    for (int j = 0; j < m; j += 16) {
      const int eA = j + q, eB = j + 4 + q, eC = j + 8 + q, eD = j + 12 + q;
      const int sA = __shfl(idx, min(eA, m - 1));
      const int sB = __shfl(idx, min(eB, m - 1));
      const int sC = __shfl(idx, min(eC, m - 1));
      const int sD = __shfl(idx, min(eD, m - 1));
      const float wA = (eA < m) ? 1.f : 0.f;
      const float wB = (eB < m) ? 1.f : 0.f;
      const float wC = (eC < m) ? 1.f : 0.f;
      const float wD = (eD < m) ? 1.f : 0.f;
      float4 vA = *reinterpret_cast<const float4*>(&P[(size_t)sA * 64 + ql * 4]);
      float4 vB = *reinterpret_cast<const float4*>(&P[(size_t)sB * 64 + ql * 4]);
      float4 vC = *reinterpret_cast<const float4*>(&P[(size_t)sC * 64 + ql * 4]);
      float4 vD = *reinterpret_cast<const float4*>(&P[(size_t)sD * 64 + ql * 4]);
      a0.x = fmaf(wA, vA.x, a0.x); a0.y = fmaf(wA, vA.y, a0.y);
      a0.z = fmaf(wA, vA.z, a0.z); a0.w = fmaf(wA, vA.w, a0.w);
      a1.x = fmaf(wB, vB.x, a1.x); a1.y = fmaf(wB, vB.y, a1.y);
      a1.z = fmaf(wB, vB.z, a1.z); a1.w = fmaf(wB, vB.w, a1.w);
      a0.x = fmaf(wC, vC.x, a0.x); a0.y = fmaf(wC, vC.y, a0.y);
      a0.z = fmaf(wC, vC.z, a0.z); a0.w = fmaf(wC, vC.w, a0.w);
      a1.x = fmaf(wD, vD.x, a1.x); a1.y = fmaf(wD, vD.y, a1.y);
      a1.z = fmaf(wD, vD.z, a1.z); a1.w = fmaf(wD, vD.w, a1.w);
    }
  }

  float4 acc = make_float4(a0.x + a1.x, a0.y + a1.y, a0.z + a1.z, a0.w + a1.w);
#pragma unroll
  for (int d = 16; d < 64; d <<= 1) {
    acc.x += __shfl_xor(acc.x, d);
    acc.y += __shfl_xor(acc.y, d);
    acc.z += __shfl_xor(acc.z, d);
    acc.w += __shfl_xor(acc.w, d);
  }

  if (q == 0) {
    const float dv = fmaxf((float)deg, 1.0f);
    float4 r4 = *reinterpret_cast<const float4*>(&R[(size_t)wid * 64 + ql * 4]);
    float4 b4 = *reinterpret_cast<const float4*>(&bias[ql * 4]);
    float4 o;
    o.x = fmaxf(acc.x / dv + b4.x + r4.x, 0.f);
    o.y = fmaxf(acc.y / dv + b4.y + r4.y, 0.f);
    o.z = fmaxf(acc.z / dv + b4.z + r4.z, 0.f);
    o.w = fmaxf(acc.w / dv + b4.w + r4.w, 0.f);
    *reinterpret_cast<float4*>(&h[(size_t)wid * 64 + ql * 4]) = o;
    if (keys != nullptr && ql == 15) keys[wid] = o.w;  // feature 63
  }
}

// one block (256 thr) per graph: stable top-30, conv1d (conflict-free weights),
// MLP head. Keys come from the compact keys[] array (coalesced).
__global__ __launch_bounds__(256) void head_kernel(const float* __restrict__ h,
                                                   const float* __restrict__ keysArr,
                                                   const float* __restrict__ cw,
                                                   const float* __restrict__ cb,
                                                   const float* __restrict__ w1,
                                                   const float* __restrict__ bb1,
                                                   const float* __restrict__ w2,
                                                   const float* __restrict__ bb2,
                                                   float* __restrict__ out) {
  __shared__ float key[PERG];
  __shared__ int sel[KK];
  __shared__ float feat[34 * 65];   // rows 30..33 garbage-read only by dead lanes
  __shared__ float cwT[192 * 33];   // [k][o] padded: conflict-free stage + read
  __shared__ float z[896];          // conv output, flat q = o*28+p
  __shared__ float psum[256];
  const int g = blockIdx.x;
  const int t = threadIdx.x;

  for (int idx = t; idx < 32 * 192; idx += 256) {
    int o = idx / 192, k = idx % 192;
    cwT[k * 33 + o] = cw[idx];
  }
  if (t < PERG) key[t] = keysArr[g * PERG + t];
  __syncthreads();

  if (t < PERG) {
    float kv = key[t];
    int r = 0;
    for (int m = 0; m < PERG; ++m) {
      float km = key[m];
      r += (int)((km > kv) || (km == kv && m < t));
    }
    if (r < KK) sel[r] = t;
  }
  __syncthreads();

  for (int idx = t; idx < KK * HH; idx += 256) {
    int r = idx >> 6, f = idx & 63;
    feat[r * 65 + f] = h[(size_t)(g * PERG + sel[r]) * HH + f];
  }
  __syncthreads();

  {
    const int o = t & 31;
    const int pg = t >> 5;  // 0..7
    float zacc[4] = {0.f, 0.f, 0.f, 0.f};
    int i = 0, tt = 0;
    for (int k = 0; k < 192; ++k) {
      float c = cwT[k * 33 + o];
#pragma unroll
      for (int j = 0; j < 4; ++j) {
        int p = pg + 8 * j;
        zacc[j] = fmaf(c, feat[(p + tt) * 65 + i], zacc[j]);
      }
      if (++tt == 3) {
        tt = 0;
        ++i;
      }
    }
    float cbo = cb[o];
#pragma unroll
    for (int j = 0; j < 4; ++j) {
      int p = pg + 8 * j;
      if (p < 28) z[o * 28 + p] = fmaxf(zacc[j] + cbo, 0.f);
    }
  }
  __syncthreads();

  {
    const int hh = t & 63;
    const int quarter = t >> 6;
    const int q0 = quarter * 224;
    float acc = 0.f;
    for (int q = 0; q < 224; ++q)
      acc = fmaf(z[q0 + q], w1[(size_t)(q0 + q) * 64 + hh], acc);
    psum[t] = acc;
  }
  __syncthreads();

  if (t < 64) {
    float o1 = fmaxf(bb1[t] + psum[t] + psum[t + 64] + psum[t + 128] + psum[t + 192], 0.f);
    float v = o1 * w2[t];
#pragma unroll
    for (int off = 32; off > 0; off >>= 1) v += __shfl_down(v, off);
    if (t == 0) out[g] = v + bb2[0];
  }
}

extern "C" void kernel_launch(void* const* d_in, const int* in_sizes, int n_in,
                              void* d_out, int out_size, void* d_ws, size_t ws_size,
                              hipStream_t stream) {
  const float* x = (const float*)d_in[0];
  const int* src = (const int*)d_in[1];
  const int* dst = (const int*)d_in[2];
  const float* wl1 = (const float*)d_in[4];
  const float* wr1 = (const float*)d_in[5];
  const float* b1 = (const float*)d_in[6];
  const float* wl2 = (const float*)d_in[7];
  const float* wr2 = (const float*)d_in[8];
  const float* b2 = (const float*)d_in[9];
  const float* wl3 = (const float*)d_in[10];
  const float* wr3 = (const float*)d_in[11];
  const float* b3 = (const float*)d_in[12];
  const float* cw = (const float*)d_in[13];
  const float* cb = (const float*)d_in[14];
  const float* w1 = (const float*)d_in[15];
  const float* bb1 = (const float*)d_in[16];
  const float* w2 = (const float*)d_in[17];
  const float* bb2 = (const float*)d_in[18];
  float* out = (float*)d_out;

  char* w = (char*)d_ws;
  auto carve = [&](size_t bytes) {
    char* p = w;
    w += (bytes + 255) & ~(size_t)255;
    return p;
  };
  int* row_start = (int*)carve((size_t)NN * 4);
  int* cnt = (int*)carve((size_t)NN * 4);
  int* eidx = (int*)carve((size_t)EE * 4);
  float* P = (float*)carve((size_t)NN * 64 * 4);
  float* R = (float*)carve((size_t)NN * 64 * 4);
  float* hbuf = (float*)carve((size_t)NN * 64 * 4);
  float* keys = (float*)carve((size_t)NN * 4);
  int* gcur = (int*)carve((size_t)NB * 4);
  int* bbase = (int*)carve((size_t)NB * 4);
  int* pairs = (int*)P;  // aliases P (csr finishes before proj1 writes P)

  zero_int<<<1, 1024, 0, stream>>>(gcur, NB);
  bucket_kernel<<<(EE + CHB - 1) / CHB, 256, 0, stream>>>(src, dst, gcur, pairs);
  bucket_scan<<<1, 1024, 0, stream>>>(gcur, bbase);
  csr_kernel<<<NB, 256, 0, stream>>>(gcur, bbase, pairs, row_start, cnt, eidx);

  const int projGrid = (NN + 63) / 64;
  const int aggGrid = (NN + 3) / 4;
  proj_kernel<128><<<projGrid, 256, 0, stream>>>(x, wl1, wr1, P, R);
  agg_kernel<<<aggGrid, 256, 0, stream>>>(P, R, b1, row_start, cnt, eidx, hbuf, nullptr);
  proj_kernel<64><<<projGrid, 256, 0, stream>>>(hbuf, wl2, wr2, P, R);
  agg_kernel<<<aggGrid, 256, 0, stream>>>(P, R, b2, row_start, cnt, eidx, hbuf, nullptr);
  proj_kernel<64><<<projGrid, 256, 0, stream>>>(hbuf, wl3, wr3, P, R);
  agg_kernel<<<aggGrid, 256, 0, stream>>>(P, R, b3, row_start, cnt, eidx, hbuf, keys);
  head_kernel<<<GG, 256, 0, stream>>>(hbuf, keys, cw, cb, w1, bb1, w2, bb2, out);
}